// Round 3
// baseline (164.301 us; speedup 1.0000x reference)
//
#include <hip/hip_runtime.h>
#include <hip/hip_fp16.h>
#include <math.h>

#define BB 16
#define TT 128
#define II 8
#define DD 128
#define XSTRIDE 65   // half2 stride per x-row (padded: kills LDS write conflicts)
#define SCALE 0.08838834764831845f  // 1/sqrt(128)

// out layout: embeddings (T,B,D) [262144] | padding_mask (B,T) [2048]
//             | sequence_mask (T,B,1) [2048] | global_mask (T) [128]

// tanh-gelu via hardware exp: tanh(v) = 1 - 2/(e^{2v}+1)
__device__ __forceinline__ float fast_gelu(float x) {
    float u = 1.5957691216057308f * x * (1.0f + 0.044715f * x * x);
    float e = __expf(u);
    float th = 1.0f - __fdividef(2.0f, e + 1.0f);
    return 0.5f * x * (1.0f + th);
}

// M[a][e] = sum_d Wq[a][d] * Wk[e][d]   (kq = x_diag @ M)
__global__ void k0_compute_M(const float* __restrict__ Wq,
                             const float* __restrict__ Wk,
                             float* __restrict__ M) {
    __shared__ float wq[DD];
    int a = blockIdx.x, e = threadIdx.x;
    wq[e] = Wq[a * DD + e];
    __syncthreads();
    const float4* wk4 = (const float4*)(Wk + e * DD);
    float acc = 0.0f;
    #pragma unroll 8
    for (int d4 = 0; d4 < DD / 4; d4++) {
        float4 w = wk4[d4];
        acc += wq[d4 * 4 + 0] * w.x + wq[d4 * 4 + 1] * w.y +
               wq[d4 * 4 + 2] * w.z + wq[d4 * 4 + 3] * w.w;
    }
    M[a * DD + e] = acc;
}

__global__ __launch_bounds__(256, 4)
void k_fused(const float* __restrict__ vectors,
             const int* __restrict__ mask,
             const float* __restrict__ We,
             const float* __restrict__ be,
             const float* __restrict__ g1,
             const float* __restrict__ b1,
             const float* __restrict__ Wv,
             const float* __restrict__ Wo,
             const float* __restrict__ bo,
             const float* __restrict__ g2,
             const float* __restrict__ b2,
             const float* __restrict__ Mws,
             float* __restrict__ out) {
    __shared__ __half2 xsh2[TT * XSTRIDE];  // ~33 KB: x rows fp16, padded stride
    __shared__ float xr[DD];                // diag row fp32
    __shared__ float kqacc[DD];             // kq * 1/sqrt(D)  (atomic accum)
    __shared__ float svacc[DD];             // s = sum_c w_c x_c
    __shared__ float embacc[DD];            // emb = s @ Wv
    __shared__ float hacc[DD];              // h_pre = emb @ Wo
    __shared__ float lgt[TT];               // masked logits
    __shared__ float wgt[TT];               // softmax weights

    int rb = blockIdx.x;
    int r = rb >> 4, b = rb & 15;
    int t = threadIdx.x;
    int wave = t >> 6, lane = t & 63;
    int half = lane >> 5, sub = lane & 31;
    int dl = sub * 4;                        // 4 d-elements per lane (32-lane row group)

    const int* mrow = mask + b * TT * TT + r * TT;
    const float4* vb4 = (const float4*)(vectors + (((long)b * TT + r) * TT) * II);

    if (t < DD) { kqacc[t] = 0.0f; svacc[t] = 0.0f; embacc[t] = 0.0f; hacc[t] = 0.0f; }

    // per-lane params for the 4-element d-slice
    float4 we4[II];
    #pragma unroll
    for (int i = 0; i < II; i++) we4[i] = *(const float4*)(We + i * DD + dl);
    float4 be4 = *(const float4*)(be + dl);
    float4 g14 = *(const float4*)(g1 + dl);
    float4 b14 = *(const float4*)(b1 + dl);

    // ---- pre-phase: diag row x_r (redundant per wave; wave0 publishes)
    {
        float4 v0 = vb4[2 * r], v1 = vb4[2 * r + 1];
        float vv[8] = {v0.x, v0.y, v0.z, v0.w, v1.x, v1.y, v1.z, v1.w};
        float e0 = be4.x, e1 = be4.y, e2 = be4.z, e3 = be4.w;
        #pragma unroll
        for (int i = 0; i < II; i++) {
            e0 += vv[i] * we4[i].x; e1 += vv[i] * we4[i].y;
            e2 += vv[i] * we4[i].z; e3 += vv[i] * we4[i].w;
        }
        float mf = mrow[r] ? 1.0f : 0.0f;
        float a0 = fast_gelu(e0) * mf, a1 = fast_gelu(e1) * mf;
        float a2 = fast_gelu(e2) * mf, a3 = fast_gelu(e3) * mf;
        float s = (a0 + a1) + (a2 + a3);
        float q = (a0 * a0 + a1 * a1) + (a2 * a2 + a3 * a3);
        #pragma unroll
        for (int o = 16; o >= 1; o >>= 1) {
            s += __shfl_xor(s, o, 64); q += __shfl_xor(q, o, 64);
        }
        float mu = s * (1.0f / 128.0f);
        float var = q * (1.0f / 128.0f) - mu * mu;
        float rstd = rsqrtf(var + 1e-5f);
        float x0 = (a0 - mu) * rstd * g14.x + b14.x;
        float x1 = (a1 - mu) * rstd * g14.y + b14.y;
        float x2 = (a2 - mu) * rstd * g14.z + b14.z;
        float x3 = (a3 - mu) * rstd * g14.w + b14.w;
        if (t < 32) *(float4*)&xr[dl] = make_float4(x0, x1, x2, x3);
    }
    __syncthreads();  // S1

    // ---- kq = (x_r @ M) * 1/sqrt(D)   (d-pair layout, atomic accumulate)
    {
        const float2* M2 = (const float2*)Mws;
        float ax = 0.0f, ay = 0.0f;
        #pragma unroll 8
        for (int j = 0; j < 32; j++) {
            int a = (wave << 5) + j;
            float xv = xr[a];
            float2 m2 = M2[a * 64 + lane];
            ax += xv * m2.x; ay += xv * m2.y;
        }
        atomicAdd(&kqacc[2 * lane], ax * SCALE);
        atomicAdd(&kqacc[2 * lane + 1], ay * SCALE);
    }
    __syncthreads();  // S2

    // ---- u = g1*kq (per-lane 4-slice), U = sum u, C0 = sum b1*kq
    float4 kq4 = *(const float4*)&kqacc[dl];
    float4 u4 = make_float4(g14.x * kq4.x, g14.y * kq4.y, g14.z * kq4.z, g14.w * kq4.w);
    float Us, C0;
    {
        float us = (u4.x + u4.y) + (u4.z + u4.w);
        float c0 = (b14.x * kq4.x + b14.y * kq4.y) + (b14.z * kq4.z + b14.w * kq4.w);
        #pragma unroll
        for (int o = 16; o >= 1; o >>= 1) {
            us += __shfl_xor(us, o, 64); c0 += __shfl_xor(c0, o, 64);
        }
        Us = us; C0 = c0;
    }

    // ---- phase 1: build 128 x-rows + logits inline.
    // Each wave: 32 rows; per iteration one row per 32-lane half.
    for (int cc = 0; cc < 16; cc++) {
        int c = (wave << 5) + 2 * cc + half;
        float4 v0 = vb4[2 * c], v1 = vb4[2 * c + 1];
        float vv[8] = {v0.x, v0.y, v0.z, v0.w, v1.x, v1.y, v1.z, v1.w};
        float e0 = be4.x, e1 = be4.y, e2 = be4.z, e3 = be4.w;
        #pragma unroll
        for (int i = 0; i < II; i++) {
            e0 += vv[i] * we4[i].x; e1 += vv[i] * we4[i].y;
            e2 += vv[i] * we4[i].z; e3 += vv[i] * we4[i].w;
        }
        int m = mrow[c];
        float mf = m ? 1.0f : 0.0f;
        float a0 = fast_gelu(e0) * mf, a1 = fast_gelu(e1) * mf;
        float a2 = fast_gelu(e2) * mf, a3 = fast_gelu(e3) * mf;
        float s = (a0 + a1) + (a2 + a3);
        float q = (a0 * a0 + a1 * a1) + (a2 * a2 + a3 * a3);
        float p = (a0 * u4.x + a1 * u4.y) + (a2 * u4.z + a3 * u4.w);
        #pragma unroll
        for (int o = 16; o >= 1; o >>= 1) {
            s += __shfl_xor(s, o, 64);
            q += __shfl_xor(q, o, 64);
            p += __shfl_xor(p, o, 64);
        }
        float mu = s * (1.0f / 128.0f);
        float var = q * (1.0f / 128.0f) - mu * mu;
        float rstd = rsqrtf(var + 1e-5f);
        float x0 = (a0 - mu) * rstd * g14.x + b14.x;
        float x1 = (a1 - mu) * rstd * g14.y + b14.y;
        float x2 = (a2 - mu) * rstd * g14.z + b14.z;
        float x3 = (a3 - mu) * rstd * g14.w + b14.w;
        xsh2[c * XSTRIDE + sub * 2]     = __floats2half2_rn(x0, x1);
        xsh2[c * XSTRIDE + sub * 2 + 1] = __floats2half2_rn(x2, x3);
        if (sub == 0) {
            float lg = rstd * (p - mu * Us) + C0;
            bool valid = (m != 0) || (c == r);
            lgt[c] = valid ? lg : -1e9f;
        }
    }
    __syncthreads();  // S3

    // ---- softmax (wave 0)
    if (wave == 0) {
        float l0 = lgt[lane], l1 = lgt[lane + 64];
        float mx = fmaxf(l0, l1);
        #pragma unroll
        for (int o = 32; o >= 1; o >>= 1) mx = fmaxf(mx, __shfl_xor(mx, o, 64));
        float e0 = __expf(l0 - mx), e1 = __expf(l1 - mx);
        float s = e0 + e1;
        #pragma unroll
        for (int o = 32; o >= 1; o >>= 1) s += __shfl_xor(s, o, 64);
        float inv = __fdividef(1.0f, s);
        wgt[lane] = e0 * inv; wgt[lane + 64] = e1 * inv;
    }
    __syncthreads();  // S4

    // ---- s[d] = sum_c w_c x_c[d]   (d-pair layout)
    {
        float ax = 0.0f, ay = 0.0f;
        #pragma unroll 8
        for (int j = 0; j < 32; j++) {
            int c = (wave << 5) + j;
            float w = wgt[c];
            float2 xf = __half22float2(xsh2[c * XSTRIDE + lane]);
            ax += w * xf.x; ay += w * xf.y;
        }
        atomicAdd(&svacc[2 * lane], ax);
        atomicAdd(&svacc[2 * lane + 1], ay);
    }
    __syncthreads();  // S5

    // ---- emb = s @ Wv
    {
        const float2* Wv2 = (const float2*)Wv;
        float ax = 0.0f, ay = 0.0f;
        #pragma unroll 8
        for (int j = 0; j < 32; j++) {
            int a = (wave << 5) + j;
            float s = svacc[a];
            float2 w2 = Wv2[a * 64 + lane];
            ax += s * w2.x; ay += s * w2.y;
        }
        atomicAdd(&embacc[2 * lane], ax);
        atomicAdd(&embacc[2 * lane + 1], ay);
    }
    __syncthreads();  // S6

    // ---- h_pre = emb @ Wo
    {
        const float2* Wo2 = (const float2*)Wo;
        float ax = 0.0f, ay = 0.0f;
        #pragma unroll 8
        for (int j = 0; j < 32; j++) {
            int a = (wave << 5) + j;
            float s = embacc[a];
            float2 w2 = Wo2[a * 64 + lane];
            ax += s * w2.x; ay += s * w2.y;
        }
        atomicAdd(&hacc[2 * lane], ax);
        atomicAdd(&hacc[2 * lane + 1], ay);
    }
    __syncthreads();  // S7

    // ---- LN2(gelu(h_pre + bo) + emb) * seq  (wave 0) + tail outputs
    if (wave == 0) {
        float2 bo2 = ((const float2*)bo)[lane];
        float em0 = embacc[2 * lane], em1 = embacc[2 * lane + 1];
        float h0 = fast_gelu(hacc[2 * lane] + bo2.x);
        float h1 = fast_gelu(hacc[2 * lane + 1] + bo2.y);
        float z0 = h0 + em0, z1 = h1 + em1;
        float s = z0 + z1;
        float q = z0 * z0 + z1 * z1;
        #pragma unroll
        for (int o = 32; o >= 1; o >>= 1) {
            s += __shfl_xor(s, o, 64); q += __shfl_xor(q, o, 64);
        }
        float mu = s * (1.0f / 128.0f);
        float var = q * (1.0f / 128.0f) - mu * mu;
        float rstd = rsqrtf(var + 1e-5f);
        float2 g22 = ((const float2*)g2)[lane], b22 = ((const float2*)b2)[lane];
        float seqf = mrow[r] ? 1.0f : 0.0f;
        float u0 = z0 - mu, u1 = z1 - mu;
        float o0 = (u0 * rstd * g22.x + b22.x) * seqf;
        float o1 = (u1 * rstd * g22.y + b22.y) * seqf;
        ((float2*)out)[rb * 64 + lane] = make_float2(o0, o1);
        if (lane == 0) {
            out[262144 + b * TT + r] = 1.0f - seqf;   // padding_mask = !real
            out[264192 + r * BB + b] = seqf;          // sequence_mask
            if (b == 0) out[266240 + r] = 1.0f;       // global_mask
        }
    }
}

extern "C" void kernel_launch(void* const* d_in, const int* in_sizes, int n_in,
                              void* d_out, int out_size, void* d_ws, size_t ws_size,
                              hipStream_t stream) {
    const float* vectors = (const float*)d_in[0];
    const int*   mask    = (const int*)d_in[1];
    const float* W_embed = (const float*)d_in[2];
    const float* b_embed = (const float*)d_in[3];
    const float* ln1_g   = (const float*)d_in[4];
    const float* ln1_b   = (const float*)d_in[5];
    const float* Wq      = (const float*)d_in[6];
    const float* Wk      = (const float*)d_in[7];
    const float* Wv      = (const float*)d_in[8];
    const float* W_out   = (const float*)d_in[9];
    const float* b_out   = (const float*)d_in[10];
    const float* ln2_g   = (const float*)d_in[11];
    const float* ln2_b   = (const float*)d_in[12];
    float* out = (float*)d_out;

    float* M = (float*)d_ws;   // 128*128 floats

    hipLaunchKernelGGL(k0_compute_M, dim3(DD), dim3(DD), 0, stream, Wq, Wk, M);
    hipLaunchKernelGGL(k_fused, dim3(TT * BB), dim3(256), 0, stream,
                       vectors, mask, W_embed, b_embed, ln1_g, ln1_b,
                       Wv, W_out, b_out, ln2_g, ln2_b, M, out);
}